// Round 3
// baseline (1133.899 us; speedup 1.0000x reference)
//
#include <hip/hip_runtime.h>
#include <stdint.h>

#define Bsz 4
#define Nn 4096
#define Dd 512

// ---------------- K1: row inverse norms ----------------
__global__ __launch_bounds__(128) void norms_kernel(const float* __restrict__ x,
                                                    float* __restrict__ rinv) {
  int row = blockIdx.x;   // B*N rows
  int t = threadIdx.x;    // 128 threads, one float4 each (512 floats)
  const float4* xr = (const float4*)(x + (size_t)row * Dd);
  float4 v = xr[t];
  float s = v.x * v.x + v.y * v.y + v.z * v.z + v.w * v.w;
  for (int o = 32; o > 0; o >>= 1) s += __shfl_down(s, o, 64);
  __shared__ float ls[2];
  if ((t & 63) == 0) ls[t >> 6] = s;
  __syncthreads();
  if (t == 0) {
    float nrm = sqrtf(ls[0] + ls[1]);
    rinv[row] = 1.0f / fmaxf(nrm, 1e-12f);
  }
}

// ---------------- K2: symmetric fp32 GEMM (round-1 arithmetic, new schedule) ----------------
// Per-output-element fmaf chain is k-ascending and bitwise identical to the
// round-1 passing kernel. Only the LDS layout / thread->column map / buffering
// changed (value-preserving transforms).
#define BT 128
#define BKC 16
#define LDA (BT + 4)   // 132: float4-aligned rows

__global__ __launch_bounds__(256) void gemm_sym(const float* __restrict__ x,
                                                const float* __restrict__ rinv,
                                                float* __restrict__ out) {
  __shared__ __align__(16) float As[2][BKC][LDA];
  __shared__ __align__(16) float Bs[2][BKC][LDA];
  int b = blockIdx.y;
  int p = blockIdx.x;             // 0..527 upper-triangle tile pairs (T=32)
  const int T = Nn / BT;
  int ti = 0;
  while (p >= T - ti) { p -= T - ti; ti++; }
  int tj = ti + p;
  int ri0 = ti * BT, rj0 = tj * BT;
  int tid = threadIdx.x;
  int tx = tid & 15, ty = tid >> 4;      // 16x16 threads, 8x8 microtile
  const float* xb = x + (size_t)b * Nn * Dd;

  // staging map: thread loads rows r0 and r0+64, k-cols kc0..kc0+3 of each chunk
  int r0 = tid >> 2;
  int kc0 = (tid & 3) << 2;

  float acc[8][8];
#pragma unroll
  for (int u = 0; u < 8; u++)
#pragma unroll
    for (int v = 0; v < 8; v++) acc[u][v] = 0.0f;

  // preload chunk 0 into buffer 0
  float4 ca0 = *(const float4*)(xb + (size_t)(ri0 + r0) * Dd + kc0);
  float4 ca1 = *(const float4*)(xb + (size_t)(ri0 + r0 + 64) * Dd + kc0);
  float4 cb0 = *(const float4*)(xb + (size_t)(rj0 + r0) * Dd + kc0);
  float4 cb1 = *(const float4*)(xb + (size_t)(rj0 + r0 + 64) * Dd + kc0);
  As[0][kc0 + 0][r0] = ca0.x; As[0][kc0 + 1][r0] = ca0.y; As[0][kc0 + 2][r0] = ca0.z; As[0][kc0 + 3][r0] = ca0.w;
  As[0][kc0 + 0][r0 + 64] = ca1.x; As[0][kc0 + 1][r0 + 64] = ca1.y; As[0][kc0 + 2][r0 + 64] = ca1.z; As[0][kc0 + 3][r0 + 64] = ca1.w;
  Bs[0][kc0 + 0][r0] = cb0.x; Bs[0][kc0 + 1][r0] = cb0.y; Bs[0][kc0 + 2][r0] = cb0.z; Bs[0][kc0 + 3][r0] = cb0.w;
  Bs[0][kc0 + 0][r0 + 64] = cb1.x; Bs[0][kc0 + 1][r0 + 64] = cb1.y; Bs[0][kc0 + 2][r0 + 64] = cb1.z; Bs[0][kc0 + 3][r0 + 64] = cb1.w;
  __syncthreads();

  const int NCH = Dd / BKC;   // 32 chunks
  for (int c = 0; c < NCH; c++) {
    int cur = c & 1;
    float4 na0, na1, nb0, nb1;
    if (c < NCH - 1) {
      int k0 = (c + 1) * BKC;
      na0 = *(const float4*)(xb + (size_t)(ri0 + r0) * Dd + k0 + kc0);
      na1 = *(const float4*)(xb + (size_t)(ri0 + r0 + 64) * Dd + k0 + kc0);
      nb0 = *(const float4*)(xb + (size_t)(rj0 + r0) * Dd + k0 + kc0);
      nb1 = *(const float4*)(xb + (size_t)(rj0 + r0 + 64) * Dd + k0 + kc0);
    }
#pragma unroll
    for (int kk = 0; kk < BKC; kk++) {
      float a[8], bb[8];
      *(float4*)&a[0] = *(const float4*)&As[cur][kk][ty * 8];
      *(float4*)&a[4] = *(const float4*)&As[cur][kk][ty * 8 + 4];
      *(float4*)&bb[0] = *(const float4*)&Bs[cur][kk][tx * 4];          // cols tx*4+0..3
      *(float4*)&bb[4] = *(const float4*)&Bs[cur][kk][64 + tx * 4];     // cols 64+tx*4+0..3
#pragma unroll
      for (int u = 0; u < 8; u++)
#pragma unroll
        for (int v = 0; v < 8; v++)
          acc[u][v] = fmaf(a[u], bb[v], acc[u][v]);
    }
    if (c < NCH - 1) {
      int nxt = cur ^ 1;
      As[nxt][kc0 + 0][r0] = na0.x; As[nxt][kc0 + 1][r0] = na0.y; As[nxt][kc0 + 2][r0] = na0.z; As[nxt][kc0 + 3][r0] = na0.w;
      As[nxt][kc0 + 0][r0 + 64] = na1.x; As[nxt][kc0 + 1][r0 + 64] = na1.y; As[nxt][kc0 + 2][r0 + 64] = na1.z; As[nxt][kc0 + 3][r0 + 64] = na1.w;
      Bs[nxt][kc0 + 0][r0] = nb0.x; Bs[nxt][kc0 + 1][r0] = nb0.y; Bs[nxt][kc0 + 2][r0] = nb0.z; Bs[nxt][kc0 + 3][r0] = nb0.w;
      Bs[nxt][kc0 + 0][r0 + 64] = nb1.x; Bs[nxt][kc0 + 1][r0 + 64] = nb1.y; Bs[nxt][kc0 + 2][r0 + 64] = nb1.z; Bs[nxt][kc0 + 3][r0 + 64] = nb1.w;
    }
    __syncthreads();
  }

  float ra[8], rb[8];
  const float* rv = rinv + b * Nn;
#pragma unroll
  for (int u = 0; u < 8; u++) ra[u] = rv[ri0 + ty * 8 + u];
#pragma unroll
  for (int v = 0; v < 4; v++) rb[v] = rv[rj0 + tx * 4 + v];
#pragma unroll
  for (int v = 4; v < 8; v++) rb[v] = rv[rj0 + 64 + tx * 4 + (v - 4)];

  float* ob = out + (size_t)b * Nn * Nn;
  // primary write: rows ri0+ty*8+u, col groups rj0+tx*4 and rj0+64+tx*4
#pragma unroll
  for (int u = 0; u < 8; u++) {
    size_t base = (size_t)(ri0 + ty * 8 + u) * Nn;
    float4 w0, w1;
    w0.x = acc[u][0] * ra[u] * rb[0];
    w0.y = acc[u][1] * ra[u] * rb[1];
    w0.z = acc[u][2] * ra[u] * rb[2];
    w0.w = acc[u][3] * ra[u] * rb[3];
    w1.x = acc[u][4] * ra[u] * rb[4];
    w1.y = acc[u][5] * ra[u] * rb[5];
    w1.z = acc[u][6] * ra[u] * rb[6];
    w1.w = acc[u][7] * ra[u] * rb[7];
    *(float4*)(ob + base + rj0 + tx * 4) = w0;
    *(float4*)(ob + base + rj0 + 64 + tx * 4) = w1;
  }
  // mirror write (bitwise-identical expression)
  if (ti != tj) {
#pragma unroll
    for (int v = 0; v < 8; v++) {
      int colg = (v < 4) ? (rj0 + tx * 4 + v) : (rj0 + 64 + tx * 4 + (v - 4));
      size_t base = (size_t)colg * Nn + ri0 + ty * 8;
      float4 m0, m1;
      m0.x = acc[0][v] * ra[0] * rb[v];
      m0.y = acc[1][v] * ra[1] * rb[v];
      m0.z = acc[2][v] * ra[2] * rb[v];
      m0.w = acc[3][v] * ra[3] * rb[v];
      m1.x = acc[4][v] * ra[4] * rb[v];
      m1.y = acc[5][v] * ra[5] * rb[v];
      m1.z = acc[6][v] * ra[6] * rb[v];
      m1.w = acc[7][v] * ra[7] * rb[v];
      *(float4*)(ob + base) = m0;
      *(float4*)(ob + base + 4) = m1;
    }
  }
}

// ---------------- K3: register-resident rank-32 threshold + keep bitmask ----------------
__global__ __launch_bounds__(256) void select_kernel(const float* __restrict__ sim,
                                                     uint32_t* __restrict__ bm) {
  int row = blockIdx.x;   // B*N rows
  int t = threadIdx.x;    // 256
  const float4* srow = (const float4*)(sim + (size_t)row * Nn);
  uint32_t key[16];
#pragma unroll
  for (int i = 0; i < 4; i++) {
    float4 v = srow[t + i * 256];
    uint32_t b0 = __float_as_uint(v.x), b1 = __float_as_uint(v.y);
    uint32_t b2 = __float_as_uint(v.z), b3 = __float_as_uint(v.w);
    key[i * 4 + 0] = (b0 & 0x80000000u) ? ~b0 : (b0 | 0x80000000u);
    key[i * 4 + 1] = (b1 & 0x80000000u) ? ~b1 : (b1 | 0x80000000u);
    key[i * 4 + 2] = (b2 & 0x80000000u) ? ~b2 : (b2 | 0x80000000u);
    key[i * 4 + 3] = (b3 & 0x80000000u) ? ~b3 : (b3 | 0x80000000u);
  }
  __shared__ uint32_t red[4];
  __shared__ uint32_t lmask[128];
  __shared__ int eqlist[64];
  __shared__ int eqcnt;
  if (t < 128) lmask[t] = 0;
  if (t == 0) eqcnt = 0;

  // minimal S with count(key > S) <= 31  => S == 32nd-largest key
  uint32_t lo = 0, hi = 0xFFFFFFFFu;
  while (lo < hi) {
    uint32_t mid = lo + ((hi - lo) >> 1);
    int cnt = 0;
#pragma unroll
    for (int i = 0; i < 16; i++) cnt += (key[i] > mid) ? 1 : 0;
    for (int o = 32; o > 0; o >>= 1) cnt += __shfl_down(cnt, o, 64);
    __syncthreads();                       // red safe to overwrite
    if ((t & 63) == 0) red[t >> 6] = (uint32_t)cnt;
    __syncthreads();
    uint32_t total = red[0] + red[1] + red[2] + red[3];
    if (total <= 31) hi = mid; else lo = mid + 1;
  }
  uint32_t S = lo;

  int cnt = 0;
  uint32_t pat[4] = {0, 0, 0, 0};
#pragma unroll
  for (int i = 0; i < 16; i++) {
    if (key[i] > S) { pat[i >> 2] |= 1u << (i & 3); cnt++; }
    else if (key[i] == S) {
      int slot = atomicAdd(&eqcnt, 1);
      if (slot < 64) eqlist[slot] = 4 * (t + 256 * (i >> 2)) + (i & 3);
    }
  }
  for (int o = 32; o > 0; o >>= 1) cnt += __shfl_down(cnt, o, 64);
  __syncthreads();
  if ((t & 63) == 0) red[t >> 6] = (uint32_t)cnt;
#pragma unroll
  for (int g = 0; g < 4; g++)
    if (pat[g]) atomicOr(&lmask[(t + 256 * g) >> 3], pat[g] << ((t & 7) * 4));
  __syncthreads();

  if (t == 0) {
    int c = (int)(red[0] + red[1] + red[2] + red[3]);   // strictly greater than S
    int need = 32 - c;                                   // ties: lowest index first
    int d = eqcnt; if (d > 64) d = 64;
    for (int s = 0; s < need; s++) {
      int best = 0x7FFFFFFF, bi = -1;
      for (int i = 0; i < d; i++) {
        int idx = eqlist[i];
        if (idx >= 0 && idx < best) { best = idx; bi = i; }
      }
      if (bi < 0) break;
      eqlist[bi] = -1;
      lmask[best >> 5] |= (1u << (best & 31));
    }
  }
  __syncthreads();
  if (t < 128) bm[(size_t)row * 128 + t] = lmask[t];
}

// ---------------- K4: masked symmetrize, in place ----------------
__global__ __launch_bounds__(256) void finalize_kernel(float* __restrict__ out,
                                                       const uint32_t* __restrict__ bm) {
  __shared__ float Tt[64][65];
  __shared__ uint32_t kA[64][2], kB[64][2];
  int b = blockIdx.y;
  int p = blockIdx.x;             // 0..2079 (T=64)
  const int T = Nn / 64;
  int ti = 0;
  while (p >= T - ti) { p -= T - ti; ti++; }
  int tj = ti + p;
  int ri0 = ti * 64, rj0 = tj * 64;
  int t = threadIdx.x;
  const uint32_t* bmb = bm + (size_t)b * Nn * 128;
  if (t < 128) {
    kA[t >> 1][t & 1] = bmb[(size_t)(ri0 + (t >> 1)) * 128 + (rj0 >> 5) + (t & 1)];
  } else {
    int tt = t - 128;
    kB[tt >> 1][tt & 1] = bmb[(size_t)(rj0 + (tt >> 1)) * 128 + (ri0 >> 5) + (tt & 1)];
  }
  __syncthreads();
  float* ob = out + (size_t)b * Nn * Nn;
#pragma unroll
  for (int k = 0; k < 16; k++) {
    int e = k * 256 + t;
    int nl = e >> 6, ml = e & 63;
    size_t addr = (size_t)(ri0 + nl) * Nn + rj0 + ml;
    float s = ob[addr];
    uint32_t ba = (kA[nl][ml >> 5] >> (ml & 31)) & 1u;
    uint32_t bb = (kB[ml][nl >> 5] >> (nl & 31)) & 1u;
    float v = 0.5f * s * (float)(ba + bb);
    ob[addr] = v;
    Tt[ml][nl] = v;
  }
  if (ti != tj) {
    __syncthreads();
#pragma unroll
    for (int k = 0; k < 16; k++) {
      int e = k * 256 + t;
      int nl = e >> 6, ml = e & 63;
      ob[(size_t)(rj0 + nl) * Nn + ri0 + ml] = Tt[nl][ml];
    }
  }
}

extern "C" void kernel_launch(void* const* d_in, const int* in_sizes, int n_in,
                              void* d_out, int out_size, void* d_ws, size_t ws_size,
                              hipStream_t stream) {
  const float* x = (const float*)d_in[0];
  float* out = (float*)d_out;
  float* rinv = (float*)d_ws;                                  // 64 KB
  uint32_t* bm = (uint32_t*)((char*)d_ws + 65536);             // 8 MB bitmask

  norms_kernel<<<Bsz * Nn, 128, 0, stream>>>(x, rinv);
  dim3 g2(528, Bsz);
  gemm_sym<<<g2, 256, 0, stream>>>(x, rinv, out);
  select_kernel<<<Bsz * Nn, 256, 0, stream>>>(out, bm);
  dim3 g4(2080, Bsz);
  finalize_kernel<<<g4, 256, 0, stream>>>(out, bm);
}

// Round 4
// 725.691 us; speedup vs baseline: 1.5625x; 1.5625x over previous
//
#include <hip/hip_runtime.h>
#include <hip/hip_bf16.h>
#include <stdint.h>

#define Bsz 4
#define Nn 4096
#define Dd 512

typedef __attribute__((ext_vector_type(8))) short bf16x8;
typedef __attribute__((ext_vector_type(4))) float f32x4;

// ---------------- K1: row inverse norms ----------------
__global__ __launch_bounds__(128) void norms_kernel(const float* __restrict__ x,
                                                    float* __restrict__ rinv) {
  int row = blockIdx.x;   // B*N rows
  int t = threadIdx.x;    // 128 threads, one float4 each (512 floats)
  const float4* xr = (const float4*)(x + (size_t)row * Dd);
  float4 v = xr[t];
  float s = v.x * v.x + v.y * v.y + v.z * v.z + v.w * v.w;
  for (int o = 32; o > 0; o >>= 1) s += __shfl_down(s, o, 64);
  __shared__ float ls[2];
  if ((t & 63) == 0) ls[t >> 6] = s;
  __syncthreads();
  if (t == 0) {
    float nrm = sqrtf(ls[0] + ls[1]);
    rinv[row] = 1.0f / fmaxf(nrm, 1e-12f);
  }
}

// ---------------- K2: symmetric split-bf16 MFMA GEMM (round-2, values verified) ----------------
// x = hi + lo (bf16 each); x.y ~= hi.hi + hi.lo + lo.hi  (lo.lo ~2^-18/term dropped)
#define GBT 128
#define GBK 32
#define LDK 40

__device__ __forceinline__ void split_bf16(float v, short& h, short& l) {
  __hip_bfloat16 bh = __float2bfloat16(v);
  float hf = __bfloat162float(bh);
  __hip_bfloat16 bl = __float2bfloat16(v - hf);
  h = __builtin_bit_cast(short, bh);
  l = __builtin_bit_cast(short, bl);
}

__global__ __launch_bounds__(256) void gemm_sym(const float* __restrict__ x,
                                                const float* __restrict__ rinv,
                                                float* __restrict__ out) {
  __shared__ __align__(16) short Ah[GBT][LDK];
  __shared__ __align__(16) short Al[GBT][LDK];
  __shared__ __align__(16) short Bh[GBT][LDK];
  __shared__ __align__(16) short Bl[GBT][LDK];
  int b = blockIdx.y;
  int p = blockIdx.x;             // 0..527 upper-triangle tile pairs (T=32)
  const int T = Nn / GBT;
  int ti = 0;
  while (p >= T - ti) { p -= T - ti; ti++; }
  int tj = ti + p;
  int ri0 = ti * GBT, rj0 = tj * GBT;
  int tid = threadIdx.x;
  int wid = tid >> 6, lane = tid & 63;
  int wr = (wid >> 1) * 64, wc = (wid & 1) * 64;   // wave's 64x64 quadrant
  int frow = lane & 15;
  int fk8 = (lane >> 4) * 8;

  const float* xb = x + (size_t)b * Nn * Dd;

  f32x4 acc[4][4];
#pragma unroll
  for (int mt = 0; mt < 4; mt++)
#pragma unroll
    for (int nt = 0; nt < 4; nt++) acc[mt][nt] = (f32x4){0.f, 0.f, 0.f, 0.f};

  for (int k0 = 0; k0 < Dd; k0 += GBK) {
    __syncthreads();
#pragma unroll
    for (int i = 0; i < 4; i++) {
      int u = tid + i * 256;          // 1024 float4 units per 128x32 tile
      int row = u >> 3;
      int kc = (u & 7) * 4;
      float4 av = *(const float4*)(xb + (size_t)(ri0 + row) * Dd + k0 + kc);
      short h0, h1, h2, h3, l0, l1, l2, l3;
      split_bf16(av.x, h0, l0); split_bf16(av.y, h1, l1);
      split_bf16(av.z, h2, l2); split_bf16(av.w, h3, l3);
      uint2 hp, lp;
      hp.x = (uint16_t)h0 | ((uint32_t)(uint16_t)h1 << 16);
      hp.y = (uint16_t)h2 | ((uint32_t)(uint16_t)h3 << 16);
      lp.x = (uint16_t)l0 | ((uint32_t)(uint16_t)l1 << 16);
      lp.y = (uint16_t)l2 | ((uint32_t)(uint16_t)l3 << 16);
      *(uint2*)&Ah[row][kc] = hp;
      *(uint2*)&Al[row][kc] = lp;
      float4 bv = *(const float4*)(xb + (size_t)(rj0 + row) * Dd + k0 + kc);
      split_bf16(bv.x, h0, l0); split_bf16(bv.y, h1, l1);
      split_bf16(bv.z, h2, l2); split_bf16(bv.w, h3, l3);
      hp.x = (uint16_t)h0 | ((uint32_t)(uint16_t)h1 << 16);
      hp.y = (uint16_t)h2 | ((uint32_t)(uint16_t)h3 << 16);
      lp.x = (uint16_t)l0 | ((uint32_t)(uint16_t)l1 << 16);
      lp.y = (uint16_t)l2 | ((uint32_t)(uint16_t)l3 << 16);
      *(uint2*)&Bh[row][kc] = hp;
      *(uint2*)&Bl[row][kc] = lp;
    }
    __syncthreads();

    bf16x8 bhf[4], blf[4];
#pragma unroll
    for (int nt = 0; nt < 4; nt++) {
      bhf[nt] = *(const bf16x8*)&Bh[wc + nt * 16 + frow][fk8];
      blf[nt] = *(const bf16x8*)&Bl[wc + nt * 16 + frow][fk8];
    }
#pragma unroll
    for (int mt = 0; mt < 4; mt++) {
      bf16x8 ah = *(const bf16x8*)&Ah[wr + mt * 16 + frow][fk8];
      bf16x8 al = *(const bf16x8*)&Al[wr + mt * 16 + frow][fk8];
#pragma unroll
      for (int nt = 0; nt < 4; nt++) {
        acc[mt][nt] = __builtin_amdgcn_mfma_f32_16x16x32_bf16(ah, bhf[nt], acc[mt][nt], 0, 0, 0);
        acc[mt][nt] = __builtin_amdgcn_mfma_f32_16x16x32_bf16(ah, blf[nt], acc[mt][nt], 0, 0, 0);
        acc[mt][nt] = __builtin_amdgcn_mfma_f32_16x16x32_bf16(al, bhf[nt], acc[mt][nt], 0, 0, 0);
      }
    }
  }

  // epilogue: C/D layout col=lane&15, row=(lane>>4)*4+reg
  float* ob = out + (size_t)b * Nn * Nn;
  const float* rv = rinv + b * Nn;
#pragma unroll
  for (int mt = 0; mt < 4; mt++) {
    int rowg0 = ri0 + wr + mt * 16 + (lane >> 4) * 4;
    float ra0 = rv[rowg0 + 0], ra1 = rv[rowg0 + 1], ra2 = rv[rowg0 + 2], ra3 = rv[rowg0 + 3];
#pragma unroll
    for (int nt = 0; nt < 4; nt++) {
      int colg = rj0 + wc + nt * 16 + (lane & 15);
      float rbv = rv[colg];
      float v0 = (acc[mt][nt].x * ra0) * rbv;
      float v1 = (acc[mt][nt].y * ra1) * rbv;
      float v2 = (acc[mt][nt].z * ra2) * rbv;
      float v3 = (acc[mt][nt].w * ra3) * rbv;
      ob[(size_t)(rowg0 + 0) * Nn + colg] = v0;
      ob[(size_t)(rowg0 + 1) * Nn + colg] = v1;
      ob[(size_t)(rowg0 + 2) * Nn + colg] = v2;
      ob[(size_t)(rowg0 + 3) * Nn + colg] = v3;
      if (ti != tj) {
        float4 m4; m4.x = v0; m4.y = v1; m4.z = v2; m4.w = v3;
        *(float4*)&ob[(size_t)colg * Nn + rowg0] = m4;   // bitwise-identical mirror
      }
    }
  }
}

// ---------------- K3: rank-32 select with fp32 band refinement ----------------
// Robust against ~5e-7 MFMA-vs-fp32 divergence: elements within eb=6e-5 of the
// rank-32 value are re-ranked with the bitwise round-1 fp32 chain.
__global__ __launch_bounds__(256) void select_kernel(const float* __restrict__ sim,
                                                     const float* __restrict__ x,
                                                     const float* __restrict__ rinv,
                                                     uint32_t* __restrict__ bm) {
  int row = blockIdx.x;   // global row in [0, B*N)
  int t = threadIdx.x;    // 256
  const float4* srow = (const float4*)(sim + (size_t)row * Nn);
  uint32_t key[16];
#pragma unroll
  for (int i = 0; i < 4; i++) {
    float4 v = srow[t + i * 256];
    uint32_t b0 = __float_as_uint(v.x), b1 = __float_as_uint(v.y);
    uint32_t b2 = __float_as_uint(v.z), b3 = __float_as_uint(v.w);
    key[i * 4 + 0] = (b0 & 0x80000000u) ? ~b0 : (b0 | 0x80000000u);
    key[i * 4 + 1] = (b1 & 0x80000000u) ? ~b1 : (b1 | 0x80000000u);
    key[i * 4 + 2] = (b2 & 0x80000000u) ? ~b2 : (b2 | 0x80000000u);
    key[i * 4 + 3] = (b3 & 0x80000000u) ? ~b3 : (b3 | 0x80000000u);
  }
  __shared__ uint32_t red[4];
  __shared__ uint32_t lmask[128];
  __shared__ int bandIdx[128];
  __shared__ float bandV[128];
  __shared__ int bandCnt;
  if (t < 128) lmask[t] = 0;
  if (t == 0) bandCnt = 0;

  // minimal S with count(key > S) <= 31  => S == 32nd-largest key
  uint32_t lo = 0, hi = 0xFFFFFFFFu;
  while (lo < hi) {
    uint32_t mid = lo + ((hi - lo) >> 1);
    int cnt = 0;
#pragma unroll
    for (int i = 0; i < 16; i++) cnt += (key[i] > mid) ? 1 : 0;
    for (int o = 32; o > 0; o >>= 1) cnt += __shfl_down(cnt, o, 64);
    __syncthreads();
    if ((t & 63) == 0) red[t >> 6] = (uint32_t)cnt;
    __syncthreads();
    uint32_t total = red[0] + red[1] + red[2] + red[3];
    if (total <= 31) hi = mid; else lo = mid + 1;
  }
  uint32_t S = lo;

  uint32_t sb = (S & 0x80000000u) ? (S & 0x7FFFFFFFu) : ~S;
  float Sval = __uint_as_float(sb);
  const float eb = 6e-5f;
  float hiT = Sval + eb, loT = Sval - eb;

  int aCnt = 0;
  uint32_t pat[4] = {0, 0, 0, 0};
#pragma unroll
  for (int i = 0; i < 16; i++) {
    uint32_t kb = (key[i] & 0x80000000u) ? (key[i] & 0x7FFFFFFFu) : ~key[i];
    float v = __uint_as_float(kb);
    if (v > hiT) { pat[i >> 2] |= 1u << (i & 3); aCnt++; }
    else if (v >= loT) {
      int s = atomicAdd(&bandCnt, 1);
      if (s < 128) bandIdx[s] = 4 * (t + 256 * (i >> 2)) + (i & 3);
    }
  }
  for (int o = 32; o > 0; o >>= 1) aCnt += __shfl_down(aCnt, o, 64);
  __syncthreads();
  if ((t & 63) == 0) red[t >> 6] = (uint32_t)aCnt;
#pragma unroll
  for (int g = 0; g < 4; g++)
    if (pat[g]) atomicOr(&lmask[(t + 256 * g) >> 3], pat[g] << ((t & 7) * 4));
  __syncthreads();

  int A = (int)(red[0] + red[1] + red[2] + red[3]);   // robustly above
  int BC = bandCnt; if (BC > 128) BC = 128;
  int need = 32 - A;                                   // 1 <= need <= BC
  bool heavy = (BC > need);
  if (heavy) {
    // recompute band sims with the bitwise round-1 fp32 chain
    const float* xn = x + (size_t)row * Dd;
    float ra = rinv[row];
    int bb = row >> 12;
    const float* xbb = x + ((size_t)bb << 12) * Dd;
    for (int s = t; s < BC; s += 256) {
      int m = bandIdx[s];
      const float* xm = xbb + (size_t)m * Dd;
      float dot = 0.f;
      for (int k = 0; k < Dd; k += 4) {
        float4 a4 = *(const float4*)(xn + k);
        float4 b4 = *(const float4*)(xm + k);
        dot = fmaf(a4.x, b4.x, dot);
        dot = fmaf(a4.y, b4.y, dot);
        dot = fmaf(a4.z, b4.z, dot);
        dot = fmaf(a4.w, b4.w, dot);
      }
      bandV[s] = (dot * ra) * rinv[((size_t)bb << 12) + m];
    }
  }
  __syncthreads();
  if (t == 0) {
    if (!heavy) {
      for (int s = 0; s < BC; s++) {
        int g = bandIdx[s];
        lmask[g >> 5] |= 1u << (g & 31);
      }
    } else {
      for (int s = 0; s < need; s++) {   // top-need by (value desc, index asc)
        float bv = -1e30f; int bidx = 0x7FFFFFFF, bs = -1;
        for (int q = 0; q < BC; q++) {
          int g = bandIdx[q];
          if (g < 0) continue;
          float v = bandV[q];
          if (v > bv || (v == bv && g < bidx)) { bv = v; bidx = g; bs = q; }
        }
        if (bs < 0) break;
        bandIdx[bs] = -1;
        lmask[bidx >> 5] |= 1u << (bidx & 31);
      }
    }
  }
  __syncthreads();
  if (t < 128) bm[(size_t)row * 128 + t] = lmask[t];
}

// ---------------- K4: masked symmetrize, in place ----------------
__global__ __launch_bounds__(256) void finalize_kernel(float* __restrict__ out,
                                                       const uint32_t* __restrict__ bm) {
  __shared__ float Tt[64][65];
  __shared__ uint32_t kA[64][2], kB[64][2];
  int b = blockIdx.y;
  int p = blockIdx.x;             // 0..2079 (T=64)
  const int T = Nn / 64;
  int ti = 0;
  while (p >= T - ti) { p -= T - ti; ti++; }
  int tj = ti + p;
  int ri0 = ti * 64, rj0 = tj * 64;
  int t = threadIdx.x;
  const uint32_t* bmb = bm + (size_t)b * Nn * 128;
  if (t < 128) {
    kA[t >> 1][t & 1] = bmb[(size_t)(ri0 + (t >> 1)) * 128 + (rj0 >> 5) + (t & 1)];
  } else {
    int tt = t - 128;
    kB[tt >> 1][tt & 1] = bmb[(size_t)(rj0 + (tt >> 1)) * 128 + (ri0 >> 5) + (tt & 1)];
  }
  __syncthreads();
  float* ob = out + (size_t)b * Nn * Nn;
#pragma unroll
  for (int k = 0; k < 16; k++) {
    int e = k * 256 + t;
    int nl = e >> 6, ml = e & 63;
    size_t addr = (size_t)(ri0 + nl) * Nn + rj0 + ml;
    float s = ob[addr];
    uint32_t ba = (kA[nl][ml >> 5] >> (ml & 31)) & 1u;
    uint32_t bb = (kB[ml][nl >> 5] >> (nl & 31)) & 1u;
    float v = 0.5f * s * (float)(ba + bb);
    ob[addr] = v;
    Tt[ml][nl] = v;
  }
  if (ti != tj) {
    __syncthreads();
#pragma unroll
    for (int k = 0; k < 16; k++) {
      int e = k * 256 + t;
      int nl = e >> 6, ml = e & 63;
      ob[(size_t)(rj0 + nl) * Nn + ri0 + ml] = Tt[nl][ml];
    }
  }
}

extern "C" void kernel_launch(void* const* d_in, const int* in_sizes, int n_in,
                              void* d_out, int out_size, void* d_ws, size_t ws_size,
                              hipStream_t stream) {
  const float* x = (const float*)d_in[0];
  float* out = (float*)d_out;
  float* rinv = (float*)d_ws;                                  // 64 KB
  uint32_t* bm = (uint32_t*)((char*)d_ws + 65536);             // 8 MB bitmask

  norms_kernel<<<Bsz * Nn, 128, 0, stream>>>(x, rinv);
  dim3 g2(528, Bsz);
  gemm_sym<<<g2, 256, 0, stream>>>(x, rinv, out);
  select_kernel<<<Bsz * Nn, 256, 0, stream>>>(out, x, rinv, bm);
  dim3 g4(2080, Bsz);
  finalize_kernel<<<g4, 256, 0, stream>>>(out, bm);
}

// Round 5
// 626.425 us; speedup vs baseline: 1.8101x; 1.1585x over previous
//
#include <hip/hip_runtime.h>
#include <hip/hip_bf16.h>
#include <stdint.h>

#define Bsz 4
#define Nn 4096
#define Dd 512

typedef __attribute__((ext_vector_type(8))) short bf16x8;
typedef __attribute__((ext_vector_type(4))) float f32x4;

// ---------------- K1: row inverse norms ----------------
__global__ __launch_bounds__(128) void norms_kernel(const float* __restrict__ x,
                                                    float* __restrict__ rinv) {
  int row = blockIdx.x;   // B*N rows
  int t = threadIdx.x;    // 128 threads, one float4 each (512 floats)
  const float4* xr = (const float4*)(x + (size_t)row * Dd);
  float4 v = xr[t];
  float s = v.x * v.x + v.y * v.y + v.z * v.z + v.w * v.w;
  for (int o = 32; o > 0; o >>= 1) s += __shfl_down(s, o, 64);
  __shared__ float ls[2];
  if ((t & 63) == 0) ls[t >> 6] = s;
  __syncthreads();
  if (t == 0) {
    float nrm = sqrtf(ls[0] + ls[1]);
    rinv[row] = 1.0f / fmaxf(nrm, 1e-12f);
  }
}

// ---------------- K2: symmetric split-bf16 MFMA GEMM (verified rounds 2/4) ----------------
#define GBT 128
#define GBK 32
#define LDK 40

__device__ __forceinline__ void split_bf16(float v, short& h, short& l) {
  __hip_bfloat16 bh = __float2bfloat16(v);
  float hf = __bfloat162float(bh);
  __hip_bfloat16 bl = __float2bfloat16(v - hf);
  h = __builtin_bit_cast(short, bh);
  l = __builtin_bit_cast(short, bl);
}

__global__ __launch_bounds__(256) void gemm_sym(const float* __restrict__ x,
                                                const float* __restrict__ rinv,
                                                float* __restrict__ out) {
  __shared__ __align__(16) short Ah[GBT][LDK];
  __shared__ __align__(16) short Al[GBT][LDK];
  __shared__ __align__(16) short Bh[GBT][LDK];
  __shared__ __align__(16) short Bl[GBT][LDK];
  int b = blockIdx.y;
  int p = blockIdx.x;             // 0..527 upper-triangle tile pairs (T=32)
  const int T = Nn / GBT;
  int ti = 0;
  while (p >= T - ti) { p -= T - ti; ti++; }
  int tj = ti + p;
  int ri0 = ti * GBT, rj0 = tj * GBT;
  int tid = threadIdx.x;
  int wid = tid >> 6, lane = tid & 63;
  int wr = (wid >> 1) * 64, wc = (wid & 1) * 64;   // wave's 64x64 quadrant
  int frow = lane & 15;
  int fk8 = (lane >> 4) * 8;

  const float* xb = x + (size_t)b * Nn * Dd;

  f32x4 acc[4][4];
#pragma unroll
  for (int mt = 0; mt < 4; mt++)
#pragma unroll
    for (int nt = 0; nt < 4; nt++) acc[mt][nt] = (f32x4){0.f, 0.f, 0.f, 0.f};

  for (int k0 = 0; k0 < Dd; k0 += GBK) {
    __syncthreads();
#pragma unroll
    for (int i = 0; i < 4; i++) {
      int u = tid + i * 256;          // 1024 float4 units per 128x32 tile
      int row = u >> 3;
      int kc = (u & 7) * 4;
      float4 av = *(const float4*)(xb + (size_t)(ri0 + row) * Dd + k0 + kc);
      short h0, h1, h2, h3, l0, l1, l2, l3;
      split_bf16(av.x, h0, l0); split_bf16(av.y, h1, l1);
      split_bf16(av.z, h2, l2); split_bf16(av.w, h3, l3);
      uint2 hp, lp;
      hp.x = (uint16_t)h0 | ((uint32_t)(uint16_t)h1 << 16);
      hp.y = (uint16_t)h2 | ((uint32_t)(uint16_t)h3 << 16);
      lp.x = (uint16_t)l0 | ((uint32_t)(uint16_t)l1 << 16);
      lp.y = (uint16_t)l2 | ((uint32_t)(uint16_t)l3 << 16);
      *(uint2*)&Ah[row][kc] = hp;
      *(uint2*)&Al[row][kc] = lp;
      float4 bv = *(const float4*)(xb + (size_t)(rj0 + row) * Dd + k0 + kc);
      split_bf16(bv.x, h0, l0); split_bf16(bv.y, h1, l1);
      split_bf16(bv.z, h2, l2); split_bf16(bv.w, h3, l3);
      hp.x = (uint16_t)h0 | ((uint32_t)(uint16_t)h1 << 16);
      hp.y = (uint16_t)h2 | ((uint32_t)(uint16_t)h3 << 16);
      lp.x = (uint16_t)l0 | ((uint32_t)(uint16_t)l1 << 16);
      lp.y = (uint16_t)l2 | ((uint32_t)(uint16_t)l3 << 16);
      *(uint2*)&Bh[row][kc] = hp;
      *(uint2*)&Bl[row][kc] = lp;
    }
    __syncthreads();

    bf16x8 bhf[4], blf[4];
#pragma unroll
    for (int nt = 0; nt < 4; nt++) {
      bhf[nt] = *(const bf16x8*)&Bh[wc + nt * 16 + frow][fk8];
      blf[nt] = *(const bf16x8*)&Bl[wc + nt * 16 + frow][fk8];
    }
#pragma unroll
    for (int mt = 0; mt < 4; mt++) {
      bf16x8 ah = *(const bf16x8*)&Ah[wr + mt * 16 + frow][fk8];
      bf16x8 al = *(const bf16x8*)&Al[wr + mt * 16 + frow][fk8];
#pragma unroll
      for (int nt = 0; nt < 4; nt++) {
        acc[mt][nt] = __builtin_amdgcn_mfma_f32_16x16x32_bf16(ah, bhf[nt], acc[mt][nt], 0, 0, 0);
        acc[mt][nt] = __builtin_amdgcn_mfma_f32_16x16x32_bf16(ah, blf[nt], acc[mt][nt], 0, 0, 0);
        acc[mt][nt] = __builtin_amdgcn_mfma_f32_16x16x32_bf16(al, bhf[nt], acc[mt][nt], 0, 0, 0);
      }
    }
  }

  // epilogue: C/D layout col=lane&15, row=(lane>>4)*4+reg
  float* ob = out + (size_t)b * Nn * Nn;
  const float* rv = rinv + b * Nn;
#pragma unroll
  for (int mt = 0; mt < 4; mt++) {
    int rowg0 = ri0 + wr + mt * 16 + (lane >> 4) * 4;
    float ra0 = rv[rowg0 + 0], ra1 = rv[rowg0 + 1], ra2 = rv[rowg0 + 2], ra3 = rv[rowg0 + 3];
#pragma unroll
    for (int nt = 0; nt < 4; nt++) {
      int colg = rj0 + wc + nt * 16 + (lane & 15);
      float rbv = rv[colg];
      float v0 = (acc[mt][nt].x * ra0) * rbv;
      float v1 = (acc[mt][nt].y * ra1) * rbv;
      float v2 = (acc[mt][nt].z * ra2) * rbv;
      float v3 = (acc[mt][nt].w * ra3) * rbv;
      ob[(size_t)(rowg0 + 0) * Nn + colg] = v0;
      ob[(size_t)(rowg0 + 1) * Nn + colg] = v1;
      ob[(size_t)(rowg0 + 2) * Nn + colg] = v2;
      ob[(size_t)(rowg0 + 3) * Nn + colg] = v3;
      if (ti != tj) {
        float4 m4; m4.x = v0; m4.y = v1; m4.z = v2; m4.w = v3;
        *(float4*)&ob[(size_t)colg * Nn + rowg0] = m4;   // bitwise-identical mirror
      }
    }
  }
}

// ---------------- K3: compact-then-rank select with fp32 band refinement ----------------
__global__ __launch_bounds__(256) void select_kernel(const float* __restrict__ sim,
                                                     const float* __restrict__ x,
                                                     const float* __restrict__ rinv,
                                                     uint32_t* __restrict__ bm) {
  int row = blockIdx.x;   // global row in [0, B*N)
  int t = threadIdx.x;    // 256
  const float4* srow = (const float4*)(sim + (size_t)row * Nn);
  float val[16];
#pragma unroll
  for (int i = 0; i < 4; i++) {
    float4 v = srow[t + i * 256];
    val[i * 4 + 0] = v.x; val[i * 4 + 1] = v.y;
    val[i * 4 + 2] = v.z; val[i * 4 + 3] = v.w;
  }
  __shared__ float lv[2048];
  __shared__ int li[2048];
  __shared__ int red[4];
  __shared__ uint32_t lmask[128];
  __shared__ int bandIdx[128];
  __shared__ float bandV[128];
  __shared__ int listCnt, bandCnt;
  __shared__ float sS;
  if (t < 128) lmask[t] = 0;
  if (t == 0) { listCnt = 0; bandCnt = 0; }

  // --- probe a compaction threshold (descending; break at >=36 candidates) ---
  const float probes[8] = {0.08f, 0.05f, 0.02f, -0.02f, -0.1f, -0.3f, -0.7f, -2.0f};
  float theta = -2.0f;
  for (int pi = 0; pi < 8; pi++) {
    theta = probes[pi];
    int c = 0;
#pragma unroll
    for (int i = 0; i < 16; i++) c += (val[i] > theta) ? 1 : 0;
    for (int o = 32; o > 0; o >>= 1) c += __shfl_down(c, o, 64);
    __syncthreads();
    if ((t & 63) == 0) red[t >> 6] = c;
    __syncthreads();
    int total = red[0] + red[1] + red[2] + red[3];
    if (total >= 36) break;
  }

  // --- compact candidates (value, index) to LDS ---
#pragma unroll
  for (int i = 0; i < 16; i++) {
    if (val[i] > theta) {
      int s = atomicAdd(&listCnt, 1);
      if (s < 2048) { lv[s] = val[i]; li[s] = 4 * (t + 256 * (i >> 2)) + (i & 3); }
    }
  }
  __syncthreads();
  int L = listCnt; if (L > 2048) L = 2048;

  // --- exact rank of each candidate; entry with rank 31 is the 32nd largest ---
  for (int e = t; e < L; e += 256) {
    float ve = lv[e]; int ie = li[e];
    int rank = 0;
    for (int q = 0; q < L; q++) {
      float vq = lv[q];
      int iq = li[q];
      rank += ((vq > ve) || (vq == ve && iq < ie)) ? 1 : 0;
    }
    if (rank == 31) sS = ve;
  }
  __syncthreads();
  float S = sS;
  const float eb = 6e-5f;
  float hiT = S + eb, loT = S - eb;

  // --- classify ALL elements from registers (round-4 logic, passed) ---
  int aCnt = 0;
  uint32_t pat[4] = {0, 0, 0, 0};
#pragma unroll
  for (int i = 0; i < 16; i++) {
    float v = val[i];
    if (v > hiT) { pat[i >> 2] |= 1u << (i & 3); aCnt++; }
    else if (v >= loT) {
      int s = atomicAdd(&bandCnt, 1);
      if (s < 128) bandIdx[s] = 4 * (t + 256 * (i >> 2)) + (i & 3);
    }
  }
  for (int o = 32; o > 0; o >>= 1) aCnt += __shfl_down(aCnt, o, 64);
  __syncthreads();
  if ((t & 63) == 0) red[t >> 6] = aCnt;
#pragma unroll
  for (int g = 0; g < 4; g++)
    if (pat[g]) atomicOr(&lmask[(t + 256 * g) >> 3], pat[g] << ((t & 7) * 4));
  __syncthreads();

  int A = red[0] + red[1] + red[2] + red[3];   // robustly above
  int BC = bandCnt; if (BC > 128) BC = 128;
  int need = 32 - A;                            // 1 <= need <= BC
  bool heavy = (BC > need);
  if (heavy) {
    // recompute band sims with the bitwise round-1 fp32 chain
    const float* xn = x + (size_t)row * Dd;
    float ra = rinv[row];
    int bb = row >> 12;
    const float* xbb = x + ((size_t)bb << 12) * Dd;
    for (int s = t; s < BC; s += 256) {
      int m = bandIdx[s];
      const float* xm = xbb + (size_t)m * Dd;
      float dot = 0.f;
      for (int k = 0; k < Dd; k += 4) {
        float4 a4 = *(const float4*)(xn + k);
        float4 b4 = *(const float4*)(xm + k);
        dot = fmaf(a4.x, b4.x, dot);
        dot = fmaf(a4.y, b4.y, dot);
        dot = fmaf(a4.z, b4.z, dot);
        dot = fmaf(a4.w, b4.w, dot);
      }
      bandV[s] = (dot * ra) * rinv[((size_t)bb << 12) + m];
    }
  }
  __syncthreads();
  if (t == 0) {
    if (!heavy) {
      for (int s = 0; s < BC; s++) {
        int g = bandIdx[s];
        lmask[g >> 5] |= 1u << (g & 31);
      }
    } else {
      for (int s = 0; s < need; s++) {   // top-need by (value desc, index asc)
        float bv = -1e30f; int bidx = 0x7FFFFFFF, bs = -1;
        for (int q = 0; q < BC; q++) {
          int g = bandIdx[q];
          if (g < 0) continue;
          float v = bandV[q];
          if (v > bv || (v == bv && g < bidx)) { bv = v; bidx = g; bs = q; }
        }
        if (bs < 0) break;
        bandIdx[bs] = -1;
        lmask[bidx >> 5] |= 1u << (bidx & 31);
      }
    }
  }
  __syncthreads();
  if (t < 128) bm[(size_t)row * 128 + t] = lmask[t];
}

// ---------------- K4: masked symmetrize, in place (float4) ----------------
__global__ __launch_bounds__(256) void finalize_kernel(float* __restrict__ out,
                                                       const uint32_t* __restrict__ bm) {
  __shared__ float Tt[64][65];
  __shared__ uint32_t kA[64][2], kB[64][2];
  int b = blockIdx.y;
  int p = blockIdx.x;             // 0..2079 (T=64)
  const int T = Nn / 64;
  int ti = 0;
  while (p >= T - ti) { p -= T - ti; ti++; }
  int tj = ti + p;
  int ri0 = ti * 64, rj0 = tj * 64;
  int t = threadIdx.x;
  const uint32_t* bmb = bm + (size_t)b * Nn * 128;
  if (t < 128) {
    kA[t >> 1][t & 1] = bmb[(size_t)(ri0 + (t >> 1)) * 128 + (rj0 >> 5) + (t & 1)];
  } else {
    int tt = t - 128;
    kB[tt >> 1][tt & 1] = bmb[(size_t)(rj0 + (tt >> 1)) * 128 + (ri0 >> 5) + (tt & 1)];
  }
  __syncthreads();
  float* ob = out + (size_t)b * Nn * Nn;
#pragma unroll
  for (int it = 0; it < 4; it++) {
    int pq = it * 256 + t;          // 1024 float4s in the 64x64 tile
    int nl = pq >> 4;
    int ml = (pq & 15) << 2;
    size_t addr = (size_t)(ri0 + nl) * Nn + rj0 + ml;
    float4 s4 = *(const float4*)(ob + addr);
    uint32_t ka4 = kA[nl][ml >> 5] >> (ml & 31);   // bits for ml..ml+3 (same word)
    uint32_t nb = nl & 31, nw = nl >> 5;
    float4 v;
    v.x = 0.5f * s4.x * (float)((ka4 & 1u) + ((kB[ml + 0][nw] >> nb) & 1u));
    v.y = 0.5f * s4.y * (float)(((ka4 >> 1) & 1u) + ((kB[ml + 1][nw] >> nb) & 1u));
    v.z = 0.5f * s4.z * (float)(((ka4 >> 2) & 1u) + ((kB[ml + 2][nw] >> nb) & 1u));
    v.w = 0.5f * s4.w * (float)(((ka4 >> 3) & 1u) + ((kB[ml + 3][nw] >> nb) & 1u));
    *(float4*)(ob + addr) = v;
    Tt[ml + 0][nl] = v.x; Tt[ml + 1][nl] = v.y;
    Tt[ml + 2][nl] = v.z; Tt[ml + 3][nl] = v.w;
  }
  if (ti != tj) {
    __syncthreads();
#pragma unroll
    for (int it = 0; it < 4; it++) {
      int pq = it * 256 + t;
      int nl = pq >> 4;
      int ml = (pq & 15) << 2;
      float4 v;
      v.x = Tt[nl][ml + 0]; v.y = Tt[nl][ml + 1];
      v.z = Tt[nl][ml + 2]; v.w = Tt[nl][ml + 3];
      *(float4*)(ob + (size_t)(rj0 + nl) * Nn + ri0 + ml) = v;
    }
  }
}

extern "C" void kernel_launch(void* const* d_in, const int* in_sizes, int n_in,
                              void* d_out, int out_size, void* d_ws, size_t ws_size,
                              hipStream_t stream) {
  const float* x = (const float*)d_in[0];
  float* out = (float*)d_out;
  float* rinv = (float*)d_ws;                                  // 64 KB
  uint32_t* bm = (uint32_t*)((char*)d_ws + 65536);             // 8 MB bitmask

  norms_kernel<<<Bsz * Nn, 128, 0, stream>>>(x, rinv);
  dim3 g2(528, Bsz);
  gemm_sym<<<g2, 256, 0, stream>>>(x, rinv, out);
  select_kernel<<<Bsz * Nn, 256, 0, stream>>>(out, x, rinv, bm);
  dim3 g4(2080, Bsz);
  finalize_kernel<<<g4, 256, 0, stream>>>(out, bm);
}

// Round 6
// 575.425 us; speedup vs baseline: 1.9705x; 1.0886x over previous
//
#include <hip/hip_runtime.h>
#include <hip/hip_bf16.h>
#include <stdint.h>

#define Bsz 4
#define Nn 4096
#define Dd 512

typedef unsigned short u16;
typedef __attribute__((ext_vector_type(8))) short bf16x8;
typedef __attribute__((ext_vector_type(4))) float f32x4;
typedef __attribute__((address_space(3))) uint32_t lds_as;
typedef __attribute__((address_space(1))) const uint32_t gbl_as;

__device__ __forceinline__ u16 bf16_of(float v) {
  __hip_bfloat16 h = __float2bfloat16(v);
  return __builtin_bit_cast(u16, h);
}
__device__ __forceinline__ float f_of_bf16(u16 u) {
  return __uint_as_float(((uint32_t)u) << 16);
}

// ---------------- K1: normalize + split to bf16 hi/lo, store rinv ----------------
__global__ __launch_bounds__(128) void prep_kernel(const float* __restrict__ x,
                                                   float* __restrict__ rinv,
                                                   u16* __restrict__ xh,
                                                   u16* __restrict__ xl) {
  int row = blockIdx.x;   // B*N rows
  int t = threadIdx.x;    // 128 threads, one float4 each
  const float4* xr = (const float4*)(x + (size_t)row * Dd);
  float4 v = xr[t];
  float s = v.x * v.x + v.y * v.y + v.z * v.z + v.w * v.w;
  for (int o = 32; o > 0; o >>= 1) s += __shfl_down(s, o, 64);
  __shared__ float ls[2];
  if ((t & 63) == 0) ls[t >> 6] = s;
  __syncthreads();
  float ri = 1.0f / fmaxf(sqrtf(ls[0] + ls[1]), 1e-12f);
  if (t == 0) rinv[row] = ri;
  float n0 = v.x * ri, n1 = v.y * ri, n2 = v.z * ri, n3 = v.w * ri;
  u16 h0 = bf16_of(n0), h1 = bf16_of(n1), h2 = bf16_of(n2), h3 = bf16_of(n3);
  u16 l0 = bf16_of(n0 - f_of_bf16(h0));
  u16 l1 = bf16_of(n1 - f_of_bf16(h1));
  u16 l2 = bf16_of(n2 - f_of_bf16(h2));
  u16 l3 = bf16_of(n3 - f_of_bf16(h3));
  uint2 hp, lp;
  hp.x = (uint32_t)h0 | ((uint32_t)h1 << 16);
  hp.y = (uint32_t)h2 | ((uint32_t)h3 << 16);
  lp.x = (uint32_t)l0 | ((uint32_t)l1 << 16);
  lp.y = (uint32_t)l2 | ((uint32_t)l3 << 16);
  *(uint2*)(xh + (size_t)row * Dd + t * 4) = hp;
  *(uint2*)(xl + (size_t)row * Dd + t * 4) = lp;
}

// ---------------- K2: symmetric split-bf16 MFMA GEMM, global_load_lds staging ----------------
// LDS tiles (no padding, global_load_lds requirement): 4 x [128][32] bf16.
// XOR slot swizzle slot = kg ^ ((row>>1)&3) applied on the GLOBAL source address
// so ds_read_b128 fragment reads are bank-conflict-free.
__global__ __launch_bounds__(256) void gemm_sym(const u16* __restrict__ xh,
                                                const u16* __restrict__ xl,
                                                u16* __restrict__ simb) {
  __shared__ __align__(16) u16 lds[4 * 128 * 32];   // 32 KB
  int b = blockIdx.y;
  int p = blockIdx.x;             // 0..527 upper-triangle tile pairs (T=32)
  const int T = Nn / 128;
  int ti = 0;
  while (p >= T - ti) { p -= T - ti; ti++; }
  int tj = ti + p;
  int ri0 = ti * 128, rj0 = tj * 128;
  int tid = threadIdx.x, wid = tid >> 6, lane = tid & 63;
  int wr = (wid >> 1) * 64, wc = (wid & 1) * 64;   // wave's 64x64 quadrant
  int frow = lane & 15, kg = lane >> 4;

  // staging role: wave wid stages tile wid (0=Ah,1=Al,2=Bh,3=Bl)
  const u16* src = (wid & 1) ? xl : xh;
  int rbase = (wid >> 1) ? rj0 : ri0;
  const u16* sb = src + ((size_t)b * Nn + rbase) * Dd;
  u16* tb = &lds[wid * 4096];
  int lrow = lane >> 2;           // 0..15 (row within 16-row group)
  int g = lane & 3;               // LDS slot this lane fills

  f32x4 acc[4][4];
#pragma unroll
  for (int mt = 0; mt < 4; mt++)
#pragma unroll
    for (int nt = 0; nt < 4; nt++) acc[mt][nt] = (f32x4){0.f, 0.f, 0.f, 0.f};

  for (int k0 = 0; k0 < Dd; k0 += 32) {
    __syncthreads();
#pragma unroll
    for (int i = 0; i < 8; i++) {
      int r = i * 16 + lrow;
      int gs = g ^ ((r >> 1) & 3);           // global k-segment this slot holds
      const u16* gp = sb + (size_t)r * Dd + k0 + gs * 8;
      __builtin_amdgcn_global_load_lds((gbl_as*)gp, (lds_as*)(tb + i * 512), 16, 0, 0);
    }
    __syncthreads();   // drains vmcnt -> staging visible

    bf16x8 bhf[4], blf[4];
#pragma unroll
    for (int nt = 0; nt < 4; nt++) {
      int rB = wc + nt * 16 + frow;
      int offB = rB * 32 + ((kg ^ ((rB >> 1) & 3)) * 8);
      bhf[nt] = *(const bf16x8*)&lds[8192 + offB];
      blf[nt] = *(const bf16x8*)&lds[12288 + offB];
    }
#pragma unroll
    for (int mt = 0; mt < 4; mt++) {
      int rA = wr + mt * 16 + frow;
      int offA = rA * 32 + ((kg ^ ((rA >> 1) & 3)) * 8);
      bf16x8 ah = *(const bf16x8*)&lds[offA];
      bf16x8 al = *(const bf16x8*)&lds[4096 + offA];
#pragma unroll
      for (int nt = 0; nt < 4; nt++) {
        acc[mt][nt] = __builtin_amdgcn_mfma_f32_16x16x32_bf16(ah, bhf[nt], acc[mt][nt], 0, 0, 0);
        acc[mt][nt] = __builtin_amdgcn_mfma_f32_16x16x32_bf16(ah, blf[nt], acc[mt][nt], 0, 0, 0);
        acc[mt][nt] = __builtin_amdgcn_mfma_f32_16x16x32_bf16(al, bhf[nt], acc[mt][nt], 0, 0, 0);
      }
    }
  }

  // epilogue: C/D layout col=lane&15, row=(lane>>4)*4+reg; write bf16 sim
  u16* ob = simb + (size_t)b * Nn * Nn;
#pragma unroll
  for (int mt = 0; mt < 4; mt++) {
    int rowg0 = ri0 + wr + mt * 16 + (lane >> 4) * 4;
#pragma unroll
    for (int nt = 0; nt < 4; nt++) {
      int colg = rj0 + wc + nt * 16 + frow;
      u16 u0 = bf16_of(acc[mt][nt].x);
      u16 u1 = bf16_of(acc[mt][nt].y);
      u16 u2 = bf16_of(acc[mt][nt].z);
      u16 u3 = bf16_of(acc[mt][nt].w);
      ob[(size_t)(rowg0 + 0) * Nn + colg] = u0;
      ob[(size_t)(rowg0 + 1) * Nn + colg] = u1;
      ob[(size_t)(rowg0 + 2) * Nn + colg] = u2;
      ob[(size_t)(rowg0 + 3) * Nn + colg] = u3;
      if (ti != tj) {
        uint2 m;
        m.x = (uint32_t)u0 | ((uint32_t)u1 << 16);
        m.y = (uint32_t)u2 | ((uint32_t)u3 << 16);
        *(uint2*)&ob[(size_t)colg * Nn + rowg0] = m;   // bitwise-identical mirror
      }
    }
  }
}

// ---------------- K3: compact-then-rank select on bf16 sims + fp32 band refinement ----------------
__global__ __launch_bounds__(256) void select_kernel(const u16* __restrict__ simb,
                                                     const float* __restrict__ x,
                                                     const float* __restrict__ rinv,
                                                     uint32_t* __restrict__ bm) {
  int row = blockIdx.x;   // global row in [0, B*N)
  int t = threadIdx.x;    // 256
  const uint4* srow = (const uint4*)(simb + (size_t)row * Nn);
  float val[16];          // val[q*8+e] = element q*2048 + t*8 + e
#pragma unroll
  for (int q = 0; q < 2; q++) {
    uint4 u = srow[t + q * 256];
    uint32_t w0 = u.x, w1 = u.y, w2 = u.z, w3 = u.w;
    val[q * 8 + 0] = __uint_as_float((w0 & 0xFFFFu) << 16);
    val[q * 8 + 1] = __uint_as_float(w0 & 0xFFFF0000u);
    val[q * 8 + 2] = __uint_as_float((w1 & 0xFFFFu) << 16);
    val[q * 8 + 3] = __uint_as_float(w1 & 0xFFFF0000u);
    val[q * 8 + 4] = __uint_as_float((w2 & 0xFFFFu) << 16);
    val[q * 8 + 5] = __uint_as_float(w2 & 0xFFFF0000u);
    val[q * 8 + 6] = __uint_as_float((w3 & 0xFFFFu) << 16);
    val[q * 8 + 7] = __uint_as_float(w3 & 0xFFFF0000u);
  }
  __shared__ float lv[2048];
  __shared__ int li[2048];
  __shared__ int red[4];
  __shared__ uint32_t lmask[128];
  __shared__ int bandIdx[128];
  __shared__ float bandV[128];
  __shared__ int listCnt, bandCnt;
  __shared__ float sS;
  if (t < 128) lmask[t] = 0;
  if (t == 0) { listCnt = 0; bandCnt = 0; }

  // --- probe a compaction threshold (descending; break at >=36 candidates) ---
  const float probes[8] = {0.08f, 0.05f, 0.02f, -0.02f, -0.1f, -0.3f, -0.7f, -2.0f};
  float theta = -2.0f;
  for (int pi = 0; pi < 8; pi++) {
    theta = probes[pi];
    int c = 0;
#pragma unroll
    for (int i = 0; i < 16; i++) c += (val[i] > theta) ? 1 : 0;
    for (int o = 32; o > 0; o >>= 1) c += __shfl_down(c, o, 64);
    __syncthreads();
    if ((t & 63) == 0) red[t >> 6] = c;
    __syncthreads();
    int total = red[0] + red[1] + red[2] + red[3];
    if (total >= 36) break;
  }

  // --- compact candidates (value, index) to LDS ---
#pragma unroll
  for (int i = 0; i < 16; i++) {
    if (val[i] > theta) {
      int s = atomicAdd(&listCnt, 1);
      if (s < 2048) { lv[s] = val[i]; li[s] = (i >> 3) * 2048 + t * 8 + (i & 7); }
    }
  }
  __syncthreads();
  int L = listCnt; if (L > 2048) L = 2048;

  // --- exact rank of each candidate; entry with rank 31 is the 32nd largest ---
  for (int e = t; e < L; e += 256) {
    float ve = lv[e]; int ie = li[e];
    int rank = 0;
    for (int q = 0; q < L; q++) {
      float vq = lv[q];
      int iq = li[q];
      rank += ((vq > ve) || (vq == ve && iq < ie)) ? 1 : 0;
    }
    if (rank == 31) sS = ve;
  }
  __syncthreads();
  float S = sS;
  float eb = fmaxf(3e-4f, fabsf(S) * 4e-3f);   // covers 2x(bf16 half-ulp + MFMA err)
  float hiT = S + eb, loT = S - eb;

  // --- classify ALL elements; band -> exact fp32 refinement ---
  int aCnt = 0;
  uint32_t patLo = 0, patHi = 0;
#pragma unroll
  for (int i = 0; i < 16; i++) {
    float v = val[i];
    if (v > hiT) {
      if (i < 8) patLo |= 1u << i; else patHi |= 1u << (i - 8);
      aCnt++;
    } else if (v >= loT) {
      int s = atomicAdd(&bandCnt, 1);
      if (s < 128) bandIdx[s] = (i >> 3) * 2048 + t * 8 + (i & 7);
    }
  }
  for (int o = 32; o > 0; o >>= 1) aCnt += __shfl_down(aCnt, o, 64);
  __syncthreads();
  if ((t & 63) == 0) red[t >> 6] = aCnt;
  if (patLo) atomicOr(&lmask[t >> 2], patLo << ((t & 3) * 8));
  if (patHi) atomicOr(&lmask[64 + (t >> 2)], patHi << ((t & 3) * 8));
  __syncthreads();

  int A = red[0] + red[1] + red[2] + red[3];   // robustly above
  int BC = bandCnt; if (BC > 128) BC = 128;
  int need = 32 - A;                            // 1 <= need <= BC
  bool heavy = (BC > need);
  if (heavy) {
    // recompute band sims with the bitwise round-1 fp32 chain
    const float* xn = x + (size_t)row * Dd;
    float ra = rinv[row];
    int bb = row >> 12;
    const float* xbb = x + ((size_t)bb << 12) * Dd;
    for (int s = t; s < BC; s += 256) {
      int m = bandIdx[s];
      const float* xm = xbb + (size_t)m * Dd;
      float dot = 0.f;
      for (int k = 0; k < Dd; k += 4) {
        float4 a4 = *(const float4*)(xn + k);
        float4 b4 = *(const float4*)(xm + k);
        dot = fmaf(a4.x, b4.x, dot);
        dot = fmaf(a4.y, b4.y, dot);
        dot = fmaf(a4.z, b4.z, dot);
        dot = fmaf(a4.w, b4.w, dot);
      }
      bandV[s] = (dot * ra) * rinv[((size_t)bb << 12) + m];
    }
  }
  __syncthreads();
  if (t == 0) {
    if (!heavy) {
      for (int s = 0; s < BC; s++) {
        int gi = bandIdx[s];
        lmask[gi >> 5] |= 1u << (gi & 31);
      }
    } else {
      for (int s = 0; s < need; s++) {   // top-need by (value desc, index asc)
        float bv = -1e30f; int bidx = 0x7FFFFFFF, bs = -1;
        for (int q = 0; q < BC; q++) {
          int gi = bandIdx[q];
          if (gi < 0) continue;
          float v = bandV[q];
          if (v > bv || (v == bv && gi < bidx)) { bv = v; bidx = gi; bs = q; }
        }
        if (bs < 0) break;
        bandIdx[bs] = -1;
        lmask[bidx >> 5] |= 1u << (bidx & 31);
      }
    }
  }
  __syncthreads();
  if (t < 128) bm[(size_t)row * 128 + t] = lmask[t];
}

// ---------------- K4: masked symmetrize, bf16 sim -> fp32 out ----------------
__global__ __launch_bounds__(256) void finalize_kernel(const u16* __restrict__ simb,
                                                       float* __restrict__ out,
                                                       const uint32_t* __restrict__ bm) {
  __shared__ float Tt[64][65];
  __shared__ uint32_t kA[64][2], kB[64][2];
  int b = blockIdx.y;
  int p = blockIdx.x;             // 0..2079 (T=64)
  const int T = Nn / 64;
  int ti = 0;
  while (p >= T - ti) { p -= T - ti; ti++; }
  int tj = ti + p;
  int ri0 = ti * 64, rj0 = tj * 64;
  int t = threadIdx.x;
  const uint32_t* bmb = bm + (size_t)b * Nn * 128;
  if (t < 128) {
    kA[t >> 1][t & 1] = bmb[(size_t)(ri0 + (t >> 1)) * 128 + (rj0 >> 5) + (t & 1)];
  } else {
    int tt = t - 128;
    kB[tt >> 1][tt & 1] = bmb[(size_t)(rj0 + (tt >> 1)) * 128 + (ri0 >> 5) + (tt & 1)];
  }
  __syncthreads();
  const u16* sbase = simb + (size_t)b * Nn * Nn;
  float* ob = out + (size_t)b * Nn * Nn;
#pragma unroll
  for (int it = 0; it < 2; it++) {
    int pq = it * 256 + t;          // 512 ushort8-units in the 64x64 tile
    int nl = pq >> 3;
    int ml = (pq & 7) * 8;
    uint4 u = *(const uint4*)(sbase + (size_t)(ri0 + nl) * Nn + rj0 + ml);
    float s0 = __uint_as_float((u.x & 0xFFFFu) << 16), s1 = __uint_as_float(u.x & 0xFFFF0000u);
    float s2 = __uint_as_float((u.y & 0xFFFFu) << 16), s3 = __uint_as_float(u.y & 0xFFFF0000u);
    float s4 = __uint_as_float((u.z & 0xFFFFu) << 16), s5 = __uint_as_float(u.z & 0xFFFF0000u);
    float s6 = __uint_as_float((u.w & 0xFFFFu) << 16), s7 = __uint_as_float(u.w & 0xFFFF0000u);
    uint32_t ka = kA[nl][ml >> 5] >> (ml & 31);   // 8 bits, same word (ml%32 in {0,8,16,24})
    uint32_t nw = nl >> 5, nb = nl & 31;
    float4 v0, v1;
    v0.x = 0.5f * s0 * (float)(((ka >> 0) & 1u) + ((kB[ml + 0][nw] >> nb) & 1u));
    v0.y = 0.5f * s1 * (float)(((ka >> 1) & 1u) + ((kB[ml + 1][nw] >> nb) & 1u));
    v0.z = 0.5f * s2 * (float)(((ka >> 2) & 1u) + ((kB[ml + 2][nw] >> nb) & 1u));
    v0.w = 0.5f * s3 * (float)(((ka >> 3) & 1u) + ((kB[ml + 3][nw] >> nb) & 1u));
    v1.x = 0.5f * s4 * (float)(((ka >> 4) & 1u) + ((kB[ml + 4][nw] >> nb) & 1u));
    v1.y = 0.5f * s5 * (float)(((ka >> 5) & 1u) + ((kB[ml + 5][nw] >> nb) & 1u));
    v1.z = 0.5f * s6 * (float)(((ka >> 6) & 1u) + ((kB[ml + 6][nw] >> nb) & 1u));
    v1.w = 0.5f * s7 * (float)(((ka >> 7) & 1u) + ((kB[ml + 7][nw] >> nb) & 1u));
    size_t addr = (size_t)(ri0 + nl) * Nn + rj0 + ml;
    *(float4*)(ob + addr) = v0;
    *(float4*)(ob + addr + 4) = v1;
    Tt[ml + 0][nl] = v0.x; Tt[ml + 1][nl] = v0.y; Tt[ml + 2][nl] = v0.z; Tt[ml + 3][nl] = v0.w;
    Tt[ml + 4][nl] = v1.x; Tt[ml + 5][nl] = v1.y; Tt[ml + 6][nl] = v1.z; Tt[ml + 7][nl] = v1.w;
  }
  if (ti != tj) {
    __syncthreads();
#pragma unroll
    for (int it = 0; it < 4; it++) {
      int pq = it * 256 + t;
      int nl = pq >> 4;
      int ml = (pq & 15) << 2;
      float4 v;
      v.x = Tt[nl][ml + 0]; v.y = Tt[nl][ml + 1];
      v.z = Tt[nl][ml + 2]; v.w = Tt[nl][ml + 3];
      *(float4*)(ob + (size_t)(rj0 + nl) * Nn + ri0 + ml) = v;
    }
  }
}

extern "C" void kernel_launch(void* const* d_in, const int* in_sizes, int n_in,
                              void* d_out, int out_size, void* d_ws, size_t ws_size,
                              hipStream_t stream) {
  const float* x = (const float*)d_in[0];
  float* out = (float*)d_out;
  // ws layout (16B-aligned): rinv 64KB | bm 8MB | xh 16MB | xl 16MB | simb 128MB
  float* rinv = (float*)d_ws;
  uint32_t* bm = (uint32_t*)((char*)d_ws + (1u << 16));
  u16* xh = (u16*)((char*)d_ws + (1u << 16) + (8u << 20));
  u16* xl = xh + (size_t)Bsz * Nn * Dd;
  u16* simb = xl + (size_t)Bsz * Nn * Dd;

  prep_kernel<<<Bsz * Nn, 128, 0, stream>>>(x, rinv, xh, xl);
  dim3 g2(528, Bsz);
  gemm_sym<<<g2, 256, 0, stream>>>(xh, xl, simb);
  select_kernel<<<Bsz * Nn, 256, 0, stream>>>(simb, x, rinv, bm);
  dim3 g4(2080, Bsz);
  finalize_kernel<<<g4, 256, 0, stream>>>(simb, out, bm);
}